// Round 5
// baseline (247.901 us; speedup 1.0000x reference)
//
#include <hip/hip_runtime.h>
#include <hip/hip_bf16.h>
#include <math.h>

typedef float v4f __attribute__((ext_vector_type(4)));
typedef short v8s __attribute__((ext_vector_type(8)));

#define T_TOK   2048
#define DDIM    1024
#define NE      16
#define IDIM    512
#define S_ROUTED 8192
#define S_ALL   10240
#define MAXTILE 104

// ---- workspace layout (bytes) ----
#define OFF_TOPKI    0u          // 8192 ints
#define OFF_TOPKW    32768u      // 8192 floats
#define OFF_PART     65536u      // 32*16 ints
#define OFF_CBASE    69632u      // 32*16 ints
#define OFF_SEGOFF   73728u      // 18 ints
#define OFF_NTILES   74240u
#define OFF_TROW     74752u      // MAXTILE ints
#define OFF_TEND     75776u
#define OFF_TEXP     76800u
#define OFF_SLOTWT   81920u      // 8192 floats
#define OFF_S2T      114688u     // 10240 ints
#define OFF_SLOTOF   155648u     // 8192 ints -> ends ~188 KB
#define OFF_W13      (1u<<20)                    // 17*1024*1024 bf16 = 34 MB
#define SZ_W13       35651584u
#define OFF_XBF      (OFF_W13 + SZ_W13)          // 2048*1024 bf16 = 4 MB
#define OFF_YP       (1u<<20)                    // ALIAS over W13 region: 10240*1024 bf16 = 20 MB
#define OFF_H        (43u<<20)                   // 10240*512 bf16 = 10 MB
#define OFF_W2B      (56u<<20)                   // 17*512*1024 bf16 = 17 MB, ends ~73 MB

__device__ __forceinline__ unsigned short f2bf(float f) {
    unsigned int u = __float_as_uint(f);
    unsigned int r = (u + 0x7fffu + ((u >> 16) & 1u)) >> 16;
    return (unsigned short)r;
}
__device__ __forceinline__ float bf2f(unsigned short s) {
    return __uint_as_float((unsigned)s << 16);
}

// async global->LDS, 16B/lane, LDS dest = uniform base + lane*16
#define GLL16(gp, lp) __builtin_amdgcn_global_load_lds( \
    (__attribute__((address_space(1))) void*)(gp), \
    (__attribute__((address_space(3))) void*)(lp), 16, 0, 0)

// ---------------- convert: fp32 -> bf16; shared expert appended as e=16 ----------------
__global__ __launch_bounds__(256) void convert_kernel(
    const float* __restrict__ w1, const float* __restrict__ w3, const float* __restrict__ w2,
    const float* __restrict__ s1, const float* __restrict__ s3, const float* __restrict__ s2,
    unsigned short* __restrict__ w13b, unsigned short* __restrict__ w2b)
{
    size_t gid = (size_t)blockIdx.x * 256 + threadIdx.x;
    size_t i4 = gid * 4;
    const float* src;
    unsigned short* dst;
    if (blockIdx.y == 0) {
        int e = (int)(i4 >> 20);
        int rem = (int)(i4 & 1048575u);
        int r2 = rem >> 10, d = rem & 1023;
        int half = (r2 >> 6) & 1;
        int rsrc = ((r2 >> 7) << 6) + (r2 & 63);
        if (e < 16) src = (half ? w3 : w1) + ((size_t)e * 512 + rsrc) * 1024 + d;
        else        src = (half ? s3 : s1) + (size_t)rsrc * 1024 + d;
        dst = w13b + i4;
    } else {
        if (i4 >= 17u * 524288u) return;
        int e = (int)(i4 >> 19);
        int rem = (int)(i4 & 524287u);
        src = (e < 16) ? (w2 + (size_t)e * 524288 + rem) : (s2 + rem);
        dst = w2b + i4;
    }
    float4 v = *(const float4*)src;
    uint2 p;
    p.x = (unsigned)f2bf(v.x) | ((unsigned)f2bf(v.y) << 16);
    p.y = (unsigned)f2bf(v.z) | ((unsigned)f2bf(v.w) << 16);
    *(uint2*)dst = p;
}

// ---------------- gate: fp32 logits, softmax, group-limited top-4 ----------------
__global__ __launch_bounds__(256) void gate_kernel(
    const float* __restrict__ x, const float* __restrict__ gw,
    int* __restrict__ topki, float* __restrict__ topkw,
    unsigned short* __restrict__ xbf)
{
    int t = blockIdx.x;
    int tid = threadIdx.x, lane = tid & 63, wave = tid >> 6;
    const float4* xr = (const float4*)(x + (size_t)t * DDIM);
    float4 xv[4];
#pragma unroll
    for (int j = 0; j < 4; j++) xv[j] = xr[lane + 64 * j];

    __shared__ float sc[NE];
#pragma unroll
    for (int ee = 0; ee < 4; ee++) {
        int e = wave * 4 + ee;
        const float4* wr = (const float4*)(gw + (size_t)e * DDIM);
        float acc = 0.f;
#pragma unroll
        for (int j = 0; j < 4; j++) {
            float4 w = wr[lane + 64 * j];
            acc += xv[j].x * w.x + xv[j].y * w.y + xv[j].z * w.z + xv[j].w * w.w;
        }
#pragma unroll
        for (int off = 32; off; off >>= 1) acc += __shfl_down(acc, off, 64);
        if (lane == 0) sc[e] = acc;
    }
    if (wave == 0) {
#pragma unroll
        for (int j = 0; j < 4; j++) {
            int base = 4 * (lane + 64 * j);
            uint2 p;
            p.x = (unsigned)f2bf(xv[j].x) | ((unsigned)f2bf(xv[j].y) << 16);
            p.y = (unsigned)f2bf(xv[j].z) | ((unsigned)f2bf(xv[j].w) << 16);
            *(uint2*)(xbf + (size_t)t * DDIM + base) = p;
        }
    }
    __syncthreads();
    if (tid == 0) {
        float mx = sc[0];
#pragma unroll
        for (int e = 1; e < NE; e++) mx = fmaxf(mx, sc[e]);
        float sco[NE]; float sum = 0.f;
#pragma unroll
        for (int e = 0; e < NE; e++) { sco[e] = __expf(sc[e] - mx); sum += sco[e]; }
        float inv = 1.f / sum;
#pragma unroll
        for (int e = 0; e < NE; e++) sco[e] *= inv;
        float gs[4];
#pragma unroll
        for (int g = 0; g < 4; g++) {
            float m = sco[4 * g];
            m = fmaxf(m, sco[4 * g + 1]); m = fmaxf(m, sco[4 * g + 2]); m = fmaxf(m, sco[4 * g + 3]);
            gs[g] = m;
        }
        int g0 = 0;
        for (int g = 1; g < 4; g++) if (gs[g] > gs[g0]) g0 = g;
        int g1 = -1;
        for (int g = 0; g < 4; g++) { if (g == g0) continue; if (g1 < 0 || gs[g] > gs[g1]) g1 = g; }
        float ms[NE];
#pragma unroll
        for (int e = 0; e < NE; e++) {
            int g = e >> 2;
            ms[e] = (g == g0 || g == g1) ? sco[e] : 0.0f;
        }
        bool used[NE] = {false};
        for (int k = 0; k < 4; k++) {
            int best = -1;
            for (int e = 0; e < NE; e++) {
                if (used[e]) continue;
                if (best < 0 || ms[e] > ms[best]) best = e;
            }
            used[best] = true;
            topki[t * 4 + k] = best;
            topkw[t * 4 + k] = sco[best];
        }
    }
}

// ---------------- hist ----------------
__global__ __launch_bounds__(256) void hist_kernel(
    const int* __restrict__ topki, int* __restrict__ part)
{
    __shared__ int cnt[16];
    int tid = threadIdx.x, b = blockIdx.x;
    if (tid < 16) cnt[tid] = 0;
    __syncthreads();
    int e = topki[b * 256 + tid];
    int lane = tid & 63;
#pragma unroll
    for (int e0 = 0; e0 < 16; e0++) {
        unsigned long long mask = __ballot(e == e0);
        if (lane == 0) atomicAdd(&cnt[e0], __popcll(mask));
    }
    __syncthreads();
    if (tid < 16) part[b * 16 + tid] = cnt[tid];
}

// ---------------- scan ----------------
__global__ __launch_bounds__(256) void scan_kernel(
    const int* __restrict__ part, int* __restrict__ cbase, int* __restrict__ segoff,
    int* __restrict__ trow, int* __restrict__ tend, int* __restrict__ texp,
    int* __restrict__ ntp)
{
    int tid = threadIdx.x;
    __shared__ int tot[16];
    __shared__ int so[17];
    if (tid < 16) {
        int s = 0;
        for (int b = 0; b < 32; b++) s += part[b * 16 + tid];
        tot[tid] = s;
    }
    __syncthreads();
    if (tid == 0) {
        int off = 0;
        for (int e = 0; e < 16; e++) { so[e] = off; segoff[e] = off; off += tot[e]; }
        so[16] = off; segoff[16] = off; segoff[17] = off + T_TOK;
        int nt = 0;
        for (int e = 0; e < 17; e++) {
            int n = (e < 16) ? tot[e] : T_TOK;
            int base = (e < 16) ? so[e] : S_ROUTED;
            for (int m = 0; m < n; m += 128) {
                trow[nt] = base + m; tend[nt] = base + n; texp[nt] = e; nt++;
            }
        }
        *ntp = nt;
    }
    __syncthreads();
    if (tid < 16) {
        int run = so[tid];
        for (int b = 0; b < 32; b++) { cbase[b * 16 + tid] = run; run += part[b * 16 + tid]; }
    }
}

// ---------------- assign ----------------
__global__ __launch_bounds__(256) void assign_kernel(
    const int* __restrict__ topki, const float* __restrict__ topkw,
    const int* __restrict__ cbase, int* __restrict__ s2t,
    float* __restrict__ slotwt, int* __restrict__ slotof)
{
    int b = blockIdx.x, tid = threadIdx.x;
    int i = b * 256 + tid;
    int e = topki[i];
    int lane = tid & 63, wave = tid >> 6;
    __shared__ int wcnt[4][16];
    int lrank = 0;
#pragma unroll
    for (int e0 = 0; e0 < 16; e0++) {
        unsigned long long mask = __ballot(e == e0);
        if (e == e0) lrank = __popcll(mask & ((1ull << lane) - 1ull));
        if (lane == 0) wcnt[wave][e0] = __popcll(mask);
    }
    __syncthreads();
    int pre = 0;
    for (int w = 0; w < wave; w++) pre += wcnt[w][e];
    int slot = cbase[b * 16 + e] + pre + lrank;
    int t = i >> 2;
    s2t[slot] = t;
    slotwt[slot] = topkw[i];
    slotof[i] = slot;
    if ((i & 3) == 0) s2t[S_ROUTED + t] = t;
}

// ---------------- gemm1: double-buffered GLL16 K-loop ----------------
// 256 thr = 4 waves; block tile 128 rows x (64 W1-cols + 64 W3-cols); BK=64, NK=16.
__global__ __launch_bounds__(256, 2) void gemm1_kernel(
    const unsigned short* __restrict__ w13b, const unsigned short* __restrict__ xbf,
    unsigned short* __restrict__ h, const float* __restrict__ slotwt,
    const int* __restrict__ s2t,
    const int* __restrict__ trow, const int* __restrict__ tend,
    const int* __restrict__ texp, const int* __restrict__ ntp)
{
    int bid = blockIdx.x;
    int tile = bid >> 3, ct = bid & 7;
    if (tile >= *ntp) return;
    int row0 = trow[tile], rend = tend[tile], e = texp[tile];
    int n0 = ct * 64;
    const unsigned short* B = w13b + ((size_t)e << 20) + ((size_t)ct << 17);

    __shared__ __align__(16) short As[2][128 * 64];
    __shared__ __align__(16) short Bs[2][128 * 64];

    int tid = threadIdx.x;
    int lane = tid & 63, wave = tid >> 6;
    int wm = wave & 1, wn = wave >> 1;
    int mq = lane >> 4, nl = lane & 15;
    int rr = lane >> 3, cbl = (lane & 7) ^ rr;

    int tok[4];
#pragma unroll
    for (int j = 0; j < 4; j++)
        tok[j] = s2t[row0 + wave * 32 + j * 8 + rr];

    v4f acc[4][4];
#pragma unroll
    for (int i = 0; i < 4; i++)
#pragma unroll
        for (int j = 0; j < 4; j++) acc[i][j] = (v4f)0.f;

    // preload k-tile 0 into buffer 0
#pragma unroll
    for (int j = 0; j < 4; j++) {
        GLL16(xbf + (size_t)tok[j] * DDIM + cbl * 8, &As[0][wave * 2048 + j * 512]);
        GLL16(B + (size_t)(wave * 32 + j * 8 + rr) * DDIM + cbl * 8, &Bs[0][wave * 2048 + j * 512]);
    }

    for (int ki = 0; ki < 16; ki++) {
        int buf = ki & 1;
        __syncthreads();              // drains vmcnt: loads(ki) complete; prev compute done
        if (ki < 15) {
            int kc = (ki + 1) * 64;
            int nb = buf ^ 1;
#pragma unroll
            for (int j = 0; j < 4; j++) {
                GLL16(xbf + (size_t)tok[j] * DDIM + kc + cbl * 8, &As[nb][wave * 2048 + j * 512]);
                GLL16(B + (size_t)(wave * 32 + j * 8 + rr) * DDIM + kc + cbl * 8, &Bs[nb][wave * 2048 + j * 512]);
            }
        }
#pragma unroll
        for (int ks = 0; ks < 2; ks++) {
            int kb = ks * 4 + mq;
            v8s a[4], b[4];
#pragma unroll
            for (int mi = 0; mi < 4; mi++) {
                int R = wm * 64 + mi * 16 + nl;
                a[mi] = *(const v8s*)(&As[buf][R * 64 + ((kb ^ (nl & 7)) * 8)]);
            }
#pragma unroll
            for (int ni = 0; ni < 4; ni++) {
                int S = (ni >> 1) * 64 + wn * 32 + (ni & 1) * 16 + nl;  // 0,1: W1  2,3: W3
                b[ni] = *(const v8s*)(&Bs[buf][S * 64 + ((kb ^ (nl & 7)) * 8)]);
            }
#pragma unroll
            for (int mi = 0; mi < 4; mi++)
#pragma unroll
                for (int ni = 0; ni < 4; ni++)
                    acc[mi][ni] = __builtin_amdgcn_mfma_f32_16x16x32_bf16(a[mi], b[ni], acc[mi][ni], 0, 0, 0);
        }
    }
#pragma unroll
    for (int mi = 0; mi < 4; mi++) {
#pragma unroll
        for (int r = 0; r < 4; r++) {
            int srow = row0 + wm * 64 + mi * 16 + mq * 4 + r;
            if (srow < rend) {
                float g = (srow < S_ROUTED) ? slotwt[srow] : 1.0f;
#pragma unroll
                for (int ni = 0; ni < 2; ni++) {
                    float p1 = acc[mi][ni][r], p3 = acc[mi][ni + 2][r];
                    float sig = 1.f / (1.f + __expf(-p1));
                    h[(size_t)srow * IDIM + n0 + wn * 32 + ni * 16 + nl] = f2bf(p1 * sig * p3 * g);
                }
            }
        }
    }
}

// ---------------- gemm2: double-buffered GLL16, bf16 partial stores ----------------
// 256 thr = 4 waves; block tile 128 rows x 128 cols; BK=64, NK=8.
__global__ __launch_bounds__(256, 2) void gemm2_kernel(
    const unsigned short* __restrict__ w2b, const unsigned short* __restrict__ h,
    unsigned short* __restrict__ yp,
    const int* __restrict__ trow, const int* __restrict__ tend,
    const int* __restrict__ texp, const int* __restrict__ ntp)
{
    int bid = blockIdx.x;
    int tile = bid >> 3, ct = bid & 7;
    if (tile >= *ntp) return;
    int row0 = trow[tile], rend = tend[tile], e = texp[tile];
    int n0 = ct * 128;
    const unsigned short* B = w2b + ((size_t)e * DDIM + n0) * IDIM;

    __shared__ __align__(16) short As[2][128 * 64];
    __shared__ __align__(16) short Bs[2][128 * 64];

    int tid = threadIdx.x;
    int lane = tid & 63, wave = tid >> 6;
    int wm = wave & 1, wn = wave >> 1;
    int mq = lane >> 4, nl = lane & 15;
    int rr = lane >> 3, cbl = (lane & 7) ^ rr;

    v4f acc[4][4];
#pragma unroll
    for (int i = 0; i < 4; i++)
#pragma unroll
        for (int j = 0; j < 4; j++) acc[i][j] = (v4f)0.f;

#pragma unroll
    for (int j = 0; j < 4; j++) {
        GLL16(h + (size_t)(row0 + wave * 32 + j * 8 + rr) * IDIM + cbl * 8,
              &As[0][wave * 2048 + j * 512]);
        GLL16(B + (size_t)(wave * 32 + j * 8 + rr) * IDIM + cbl * 8,
              &Bs[0][wave * 2048 + j * 512]);
    }

    for (int ki = 0; ki < 8; ki++) {
        int buf = ki & 1;
        __syncthreads();
        if (ki < 7) {
            int kc = (ki + 1) * 64;
            int nb = buf ^ 1;
#pragma unroll
            for (int j = 0; j < 4; j++) {
                GLL16(h + (size_t)(row0 + wave * 32 + j * 8 + rr) * IDIM + kc + cbl * 8,
                      &As[nb][wave * 2048 + j * 512]);
                GLL16(B + (size_t)(wave * 32 + j * 8 + rr) * IDIM + kc + cbl * 8,
                      &Bs[nb][wave * 2048 + j * 512]);
            }
        }
#pragma unroll
        for (int ks = 0; ks < 2; ks++) {
            int kb = ks * 4 + mq;
            v8s a[4], b[4];
#pragma unroll
            for (int mi = 0; mi < 4; mi++) {
                int R = wm * 64 + mi * 16 + nl;
                a[mi] = *(const v8s*)(&As[buf][R * 64 + ((kb ^ (nl & 7)) * 8)]);
            }
#pragma unroll
            for (int ni = 0; ni < 4; ni++) {
                int S = wn * 64 + ni * 16 + nl;
                b[ni] = *(const v8s*)(&Bs[buf][S * 64 + ((kb ^ (nl & 7)) * 8)]);
            }
#pragma unroll
            for (int mi = 0; mi < 4; mi++)
#pragma unroll
                for (int ni = 0; ni < 4; ni++)
                    acc[mi][ni] = __builtin_amdgcn_mfma_f32_16x16x32_bf16(a[mi], b[ni], acc[mi][ni], 0, 0, 0);
        }
    }
#pragma unroll
    for (int mi = 0; mi < 4; mi++) {
#pragma unroll
        for (int r = 0; r < 4; r++) {
            int srow = row0 + wm * 64 + mi * 16 + mq * 4 + r;
            if (srow < rend) {
                unsigned short* yrow = yp + ((size_t)srow << 10) + n0 + wn * 64 + nl;
#pragma unroll
                for (int ni = 0; ni < 4; ni++)
                    yrow[ni * 16] = f2bf(acc[mi][ni][r]);
            }
        }
    }
}

// ---------------- combine: out[t] = yp[shared_t] + sum of 4 routed yp rows (bf16 in) ----------------
__global__ __launch_bounds__(256) void combine_kernel(
    const unsigned short* __restrict__ yp, const int* __restrict__ slotof,
    float* __restrict__ out)
{
    int t = blockIdx.x;
    int c = threadIdx.x * 4;
    int s0 = slotof[t * 4 + 0], s1 = slotof[t * 4 + 1];
    int s2 = slotof[t * 4 + 2], s3 = slotof[t * 4 + 3];
    ushort4 v  = *(const ushort4*)(yp + (((size_t)(S_ROUTED + t)) << 10) + c);
    ushort4 a0 = *(const ushort4*)(yp + (((size_t)s0) << 10) + c);
    ushort4 a1 = *(const ushort4*)(yp + (((size_t)s1) << 10) + c);
    ushort4 a2 = *(const ushort4*)(yp + (((size_t)s2) << 10) + c);
    ushort4 a3 = *(const ushort4*)(yp + (((size_t)s3) << 10) + c);
    float4 o;
    o.x = bf2f(v.x) + bf2f(a0.x) + bf2f(a1.x) + bf2f(a2.x) + bf2f(a3.x);
    o.y = bf2f(v.y) + bf2f(a0.y) + bf2f(a1.y) + bf2f(a2.y) + bf2f(a3.y);
    o.z = bf2f(v.z) + bf2f(a0.z) + bf2f(a1.z) + bf2f(a2.z) + bf2f(a3.z);
    o.w = bf2f(v.w) + bf2f(a0.w) + bf2f(a1.w) + bf2f(a2.w) + bf2f(a3.w);
    *(float4*)(out + (((size_t)t) << 10) + c) = o;
}

extern "C" void kernel_launch(void* const* d_in, const int* in_sizes, int n_in,
                              void* d_out, int out_size, void* d_ws, size_t ws_size,
                              hipStream_t stream) {
    const float* x    = (const float*)d_in[0];
    const float* gw   = (const float*)d_in[1];
    const float* w1   = (const float*)d_in[2];
    const float* w2   = (const float*)d_in[3];
    const float* w3   = (const float*)d_in[4];
    const float* wsh1 = (const float*)d_in[5];
    const float* wsh2 = (const float*)d_in[6];
    const float* wsh3 = (const float*)d_in[7];
    float* out = (float*)d_out;

    char* ws = (char*)d_ws;
    int*   topki  = (int*)(ws + OFF_TOPKI);
    float* topkw  = (float*)(ws + OFF_TOPKW);
    int*   part   = (int*)(ws + OFF_PART);
    int*   cbase  = (int*)(ws + OFF_CBASE);
    int*   segoff = (int*)(ws + OFF_SEGOFF);
    int*   ntp    = (int*)(ws + OFF_NTILES);
    int*   trow   = (int*)(ws + OFF_TROW);
    int*   tend   = (int*)(ws + OFF_TEND);
    int*   texp   = (int*)(ws + OFF_TEXP);
    float* slotwt = (float*)(ws + OFF_SLOTWT);
    int*   s2t    = (int*)(ws + OFF_S2T);
    int*   slotof = (int*)(ws + OFF_SLOTOF);
    unsigned short* w13b = (unsigned short*)(ws + OFF_W13);
    unsigned short* xbf  = (unsigned short*)(ws + OFF_XBF);
    unsigned short* yp   = (unsigned short*)(ws + OFF_YP);   // aliases w13b (used after gemm1)
    unsigned short* h    = (unsigned short*)(ws + OFF_H);
    unsigned short* w2b  = (unsigned short*)(ws + OFF_W2B);

    convert_kernel<<<dim3(17408, 2), 256, 0, stream>>>(w1, w3, w2, wsh1, wsh3, wsh2,
                                                       w13b, w2b);
    gate_kernel<<<T_TOK, 256, 0, stream>>>(x, gw, topki, topkw, xbf);
    hist_kernel<<<32, 256, 0, stream>>>(topki, part);
    scan_kernel<<<1, 256, 0, stream>>>(part, cbase, segoff, trow, tend, texp, ntp);
    assign_kernel<<<32, 256, 0, stream>>>(topki, topkw, cbase, s2t, slotwt, slotof);
    gemm1_kernel<<<MAXTILE * 8, 256, 0, stream>>>(w13b, xbf, h, slotwt, s2t,
                                                  trow, tend, texp, ntp);
    gemm2_kernel<<<MAXTILE * 8, 256, 0, stream>>>(w2b, h, yp, trow, tend, texp, ntp);
    combine_kernel<<<T_TOK, 256, 0, stream>>>(yp, slotof, out);
}

// Round 6
// 228.913 us; speedup vs baseline: 1.0829x; 1.0829x over previous
//
#include <hip/hip_runtime.h>
#include <hip/hip_bf16.h>
#include <math.h>

typedef float v4f __attribute__((ext_vector_type(4)));
typedef short v8s __attribute__((ext_vector_type(8)));

#define T_TOK   2048
#define DDIM    1024
#define NE      16
#define IDIM    512
#define S_ROUTED 8192
#define S_ALL   10240
#define MAXTILE 104

// ---- workspace layout (bytes) ----
#define OFF_TOPKI    0u          // 8192 ints
#define OFF_TOPKW    32768u      // 8192 floats
#define OFF_PART     65536u      // 32*16 ints
#define OFF_CBASE    69632u      // 32*16 ints
#define OFF_SEGOFF   73728u      // 18 ints
#define OFF_NTILES   74240u
#define OFF_TROW     74752u      // MAXTILE ints
#define OFF_TEND     75776u
#define OFF_TEXP     76800u
#define OFF_SLOTWT   81920u      // 8192 floats
#define OFF_S2T      114688u     // 10240 ints
#define OFF_SLOTOF   155648u     // 8192 ints
#define OFF_XBF      (1u<<20)    // 2048*1024 bf16 = 4 MB
#define OFF_H        (8u<<20)    // 10240*512 bf16 = 10 MB
#define OFF_YP       (24u<<20)   // 10240*1024 bf16 = 20 MB, ends 44 MB

__device__ __forceinline__ unsigned short f2bf(float f) {
    unsigned int u = __float_as_uint(f);
    unsigned int r = (u + 0x7fffu + ((u >> 16) & 1u)) >> 16;
    return (unsigned short)r;
}
__device__ __forceinline__ float bf2f(unsigned short s) {
    return __uint_as_float((unsigned)s << 16);
}

// async global->LDS, 16B/lane, LDS dest = uniform base + lane*16
#define GLL16(gp, lp) __builtin_amdgcn_global_load_lds( \
    (__attribute__((address_space(1))) void*)(gp), \
    (__attribute__((address_space(3))) void*)(lp), 16, 0, 0)

// ---------------- gate: fp32 logits, softmax, group-limited top-4 ----------------
__global__ __launch_bounds__(256) void gate_kernel(
    const float* __restrict__ x, const float* __restrict__ gw,
    int* __restrict__ topki, float* __restrict__ topkw,
    unsigned short* __restrict__ xbf)
{
    int t = blockIdx.x;
    int tid = threadIdx.x, lane = tid & 63, wave = tid >> 6;
    const float4* xr = (const float4*)(x + (size_t)t * DDIM);
    float4 xv[4];
#pragma unroll
    for (int j = 0; j < 4; j++) xv[j] = xr[lane + 64 * j];

    __shared__ float sc[NE];
#pragma unroll
    for (int ee = 0; ee < 4; ee++) {
        int e = wave * 4 + ee;
        const float4* wr = (const float4*)(gw + (size_t)e * DDIM);
        float acc = 0.f;
#pragma unroll
        for (int j = 0; j < 4; j++) {
            float4 w = wr[lane + 64 * j];
            acc += xv[j].x * w.x + xv[j].y * w.y + xv[j].z * w.z + xv[j].w * w.w;
        }
#pragma unroll
        for (int off = 32; off; off >>= 1) acc += __shfl_down(acc, off, 64);
        if (lane == 0) sc[e] = acc;
    }
    if (wave == 0) {
#pragma unroll
        for (int j = 0; j < 4; j++) {
            int base = 4 * (lane + 64 * j);
            uint2 p;
            p.x = (unsigned)f2bf(xv[j].x) | ((unsigned)f2bf(xv[j].y) << 16);
            p.y = (unsigned)f2bf(xv[j].z) | ((unsigned)f2bf(xv[j].w) << 16);
            *(uint2*)(xbf + (size_t)t * DDIM + base) = p;
        }
    }
    __syncthreads();
    if (tid == 0) {
        float mx = sc[0];
#pragma unroll
        for (int e = 1; e < NE; e++) mx = fmaxf(mx, sc[e]);
        float sco[NE]; float sum = 0.f;
#pragma unroll
        for (int e = 0; e < NE; e++) { sco[e] = __expf(sc[e] - mx); sum += sco[e]; }
        float inv = 1.f / sum;
#pragma unroll
        for (int e = 0; e < NE; e++) sco[e] *= inv;
        float gs[4];
#pragma unroll
        for (int g = 0; g < 4; g++) {
            float m = sco[4 * g];
            m = fmaxf(m, sco[4 * g + 1]); m = fmaxf(m, sco[4 * g + 2]); m = fmaxf(m, sco[4 * g + 3]);
            gs[g] = m;
        }
        int g0 = 0;
        for (int g = 1; g < 4; g++) if (gs[g] > gs[g0]) g0 = g;
        int g1 = -1;
        for (int g = 0; g < 4; g++) { if (g == g0) continue; if (g1 < 0 || gs[g] > gs[g1]) g1 = g; }
        float ms[NE];
#pragma unroll
        for (int e = 0; e < NE; e++) {
            int g = e >> 2;
            ms[e] = (g == g0 || g == g1) ? sco[e] : 0.0f;
        }
        bool used[NE] = {false};
        for (int k = 0; k < 4; k++) {
            int best = -1;
            for (int e = 0; e < NE; e++) {
                if (used[e]) continue;
                if (best < 0 || ms[e] > ms[best]) best = e;
            }
            used[best] = true;
            topki[t * 4 + k] = best;
            topkw[t * 4 + k] = sco[best];
        }
    }
}

// ---------------- hist ----------------
__global__ __launch_bounds__(256) void hist_kernel(
    const int* __restrict__ topki, int* __restrict__ part)
{
    __shared__ int cnt[16];
    int tid = threadIdx.x, b = blockIdx.x;
    if (tid < 16) cnt[tid] = 0;
    __syncthreads();
    int e = topki[b * 256 + tid];
    int lane = tid & 63;
#pragma unroll
    for (int e0 = 0; e0 < 16; e0++) {
        unsigned long long mask = __ballot(e == e0);
        if (lane == 0) atomicAdd(&cnt[e0], __popcll(mask));
    }
    __syncthreads();
    if (tid < 16) part[b * 16 + tid] = cnt[tid];
}

// ---------------- scan ----------------
__global__ __launch_bounds__(256) void scan_kernel(
    const int* __restrict__ part, int* __restrict__ cbase, int* __restrict__ segoff,
    int* __restrict__ trow, int* __restrict__ tend, int* __restrict__ texp,
    int* __restrict__ ntp)
{
    int tid = threadIdx.x;
    __shared__ int tot[16];
    __shared__ int so[17];
    if (tid < 16) {
        int s = 0;
        for (int b = 0; b < 32; b++) s += part[b * 16 + tid];
        tot[tid] = s;
    }
    __syncthreads();
    if (tid == 0) {
        int off = 0;
        for (int e = 0; e < 16; e++) { so[e] = off; segoff[e] = off; off += tot[e]; }
        so[16] = off; segoff[16] = off; segoff[17] = off + T_TOK;
        int nt = 0;
        for (int e = 0; e < 17; e++) {
            int n = (e < 16) ? tot[e] : T_TOK;
            int base = (e < 16) ? so[e] : S_ROUTED;
            for (int m = 0; m < n; m += 128) {
                trow[nt] = base + m; tend[nt] = base + n; texp[nt] = e; nt++;
            }
        }
        *ntp = nt;
    }
    __syncthreads();
    if (tid < 16) {
        int run = so[tid];
        for (int b = 0; b < 32; b++) { cbase[b * 16 + tid] = run; run += part[b * 16 + tid]; }
    }
}

// ---------------- assign ----------------
__global__ __launch_bounds__(256) void assign_kernel(
    const int* __restrict__ topki, const float* __restrict__ topkw,
    const int* __restrict__ cbase, int* __restrict__ s2t,
    float* __restrict__ slotwt, int* __restrict__ slotof)
{
    int b = blockIdx.x, tid = threadIdx.x;
    int i = b * 256 + tid;
    int e = topki[i];
    int lane = tid & 63, wave = tid >> 6;
    __shared__ int wcnt[4][16];
    int lrank = 0;
#pragma unroll
    for (int e0 = 0; e0 < 16; e0++) {
        unsigned long long mask = __ballot(e == e0);
        if (e == e0) lrank = __popcll(mask & ((1ull << lane) - 1ull));
        if (lane == 0) wcnt[wave][e0] = __popcll(mask);
    }
    __syncthreads();
    int pre = 0;
    for (int w = 0; w < wave; w++) pre += wcnt[w][e];
    int slot = cbase[b * 16 + e] + pre + lrank;
    int t = i >> 2;
    s2t[slot] = t;
    slotwt[slot] = topkw[i];
    slotof[i] = slot;
    if ((i & 3) == 0) s2t[S_ROUTED + t] = t;
}

// ---------------- gemm1: h = silu(X W1^T) * (X W3^T) * g ----------------
// A: bf16 xbf via GLL16 (indirect s2t). B: fp32 w1/w3 direct, reg-staged + f2bf + ds_write.
// 256 thr = 4 waves; block tile 128 rows x (64 W1-cols + 64 W3-cols); BK=64, single LDS buf.
__global__ __launch_bounds__(256, 3) void gemm1_kernel(
    const float* __restrict__ w1, const float* __restrict__ w3,
    const float* __restrict__ s1, const float* __restrict__ s3,
    const unsigned short* __restrict__ xbf,
    unsigned short* __restrict__ h, const float* __restrict__ slotwt,
    const int* __restrict__ s2t,
    const int* __restrict__ trow, const int* __restrict__ tend,
    const int* __restrict__ texp, const int* __restrict__ ntp)
{
    int bid = blockIdx.x;
    int tile = bid >> 3, ct = bid & 7;
    if (tile >= *ntp) return;
    int row0 = trow[tile], rend = tend[tile], e = texp[tile];
    int n0 = ct * 64;
    const float* B1 = (e < 16) ? (w1 + (size_t)e * 524288) : s1;
    const float* B3 = (e < 16) ? (w3 + (size_t)e * 524288) : s3;

    __shared__ __align__(16) short As[128 * 64];
    __shared__ __align__(16) short Bs[128 * 64];

    int tid = threadIdx.x;
    int lane = tid & 63, wave = tid >> 6;
    int wm = wave & 1, wn = wave >> 1;
    int mq = lane >> 4, nl = lane & 15;
    int rr = lane >> 3, cbl = (lane & 7) ^ rr;

    int tok[4];
#pragma unroll
    for (int j = 0; j < 4; j++)
        tok[j] = s2t[row0 + wave * 32 + j * 8 + rr];

    // B staging tasks: u = tid + 256j -> LDS row (u>>3) in [0,128), k-block (u&7)
    const float* bsrc[4];
    int brow[4], bblk[4];
#pragma unroll
    for (int j = 0; j < 4; j++) {
        int u = tid + 256 * j;
        brow[j] = u >> 3; bblk[j] = u & 7;
        int half = brow[j] >> 6;
        const float* base = half ? B3 : B1;
        bsrc[j] = base + (size_t)(n0 + (brow[j] & 63)) * DDIM + bblk[j] * 8;
    }

    v4f acc[4][4];
#pragma unroll
    for (int i = 0; i < 4; i++)
#pragma unroll
        for (int j = 0; j < 4; j++) acc[i][j] = (v4f)0.f;

    // preload B(0) into regs
    float4 br0[4], br1[4];
#pragma unroll
    for (int j = 0; j < 4; j++) {
        br0[j] = *(const float4*)(bsrc[j]);
        br1[j] = *(const float4*)(bsrc[j] + 4);
    }

    for (int ki = 0; ki < 16; ki++) {
        int kc = ki * 64;
        __syncthreads();                  // As/Bs free (prev compute done)
#pragma unroll
        for (int j = 0; j < 4; j++)
            GLL16(xbf + (size_t)tok[j] * DDIM + kc + cbl * 8, As + wave * 2048 + j * 512);
        // write B(ki) regs -> Bs (XOR swizzled 8-short blocks)
#pragma unroll
        for (int j = 0; j < 4; j++) {
            uint4 p;
            p.x = (unsigned)f2bf(br0[j].x) | ((unsigned)f2bf(br0[j].y) << 16);
            p.y = (unsigned)f2bf(br0[j].z) | ((unsigned)f2bf(br0[j].w) << 16);
            p.z = (unsigned)f2bf(br1[j].x) | ((unsigned)f2bf(br1[j].y) << 16);
            p.w = (unsigned)f2bf(br1[j].z) | ((unsigned)f2bf(br1[j].w) << 16);
            *(uint4*)(Bs + brow[j] * 64 + ((bblk[j] ^ (brow[j] & 7)) * 8)) = p;
        }
        __syncthreads();                  // drains A-GLL + B ds_writes
        if (ki < 15) {                    // prefetch B(ki+1); overlaps compute below
#pragma unroll
            for (int j = 0; j < 4; j++) {
                br0[j] = *(const float4*)(bsrc[j] + kc + 64);
                br1[j] = *(const float4*)(bsrc[j] + kc + 68);
            }
        }
#pragma unroll
        for (int ks = 0; ks < 2; ks++) {
            int kb = ks * 4 + mq;
            v8s a[4], b[4];
#pragma unroll
            for (int mi = 0; mi < 4; mi++) {
                int R = wm * 64 + mi * 16 + nl;
                a[mi] = *(const v8s*)(As + R * 64 + ((kb ^ (nl & 7)) * 8));
            }
#pragma unroll
            for (int ni = 0; ni < 4; ni++) {
                int S = (ni >> 1) * 64 + wn * 32 + (ni & 1) * 16 + nl;  // 0,1: W1  2,3: W3
                b[ni] = *(const v8s*)(Bs + S * 64 + ((kb ^ (nl & 7)) * 8));
            }
#pragma unroll
            for (int mi = 0; mi < 4; mi++)
#pragma unroll
                for (int ni = 0; ni < 4; ni++)
                    acc[mi][ni] = __builtin_amdgcn_mfma_f32_16x16x32_bf16(a[mi], b[ni], acc[mi][ni], 0, 0, 0);
        }
    }
#pragma unroll
    for (int mi = 0; mi < 4; mi++) {
#pragma unroll
        for (int r = 0; r < 4; r++) {
            int srow = row0 + wm * 64 + mi * 16 + mq * 4 + r;
            if (srow < rend) {
                float g = (srow < S_ROUTED) ? slotwt[srow] : 1.0f;
#pragma unroll
                for (int ni = 0; ni < 2; ni++) {
                    float p1 = acc[mi][ni][r], p3 = acc[mi][ni + 2][r];
                    float sig = 1.f / (1.f + __expf(-p1));
                    h[(size_t)srow * IDIM + n0 + wn * 32 + ni * 16 + nl] = f2bf(p1 * sig * p3 * g);
                }
            }
        }
    }
}

// ---------------- gemm2: yp = h @ W2^T ; A bf16 GLL16, B fp32 reg-staged ----------------
// 256 thr = 4 waves; block tile 128 rows x 128 out-cols; BK=64, K=512, single LDS buf.
__global__ __launch_bounds__(256, 3) void gemm2_kernel(
    const float* __restrict__ w2, const float* __restrict__ s2w,
    const unsigned short* __restrict__ h, unsigned short* __restrict__ yp,
    const int* __restrict__ trow, const int* __restrict__ tend,
    const int* __restrict__ texp, const int* __restrict__ ntp)
{
    int bid = blockIdx.x;
    int tile = bid >> 3, ct = bid & 7;
    if (tile >= *ntp) return;
    int row0 = trow[tile], rend = tend[tile], e = texp[tile];
    int n0 = ct * 128;
    const float* B = ((e < 16) ? (w2 + (size_t)e * 524288) : s2w) + (size_t)n0 * IDIM;

    __shared__ __align__(16) short As[128 * 64];
    __shared__ __align__(16) short Bs[128 * 64];

    int tid = threadIdx.x;
    int lane = tid & 63, wave = tid >> 6;
    int wm = wave & 1, wn = wave >> 1;
    int mq = lane >> 4, nl = lane & 15;
    int rr = lane >> 3, cbl = (lane & 7) ^ rr;

    const float* bsrc[4];
    int brow[4], bblk[4];
#pragma unroll
    for (int j = 0; j < 4; j++) {
        int u = tid + 256 * j;
        brow[j] = u >> 3; bblk[j] = u & 7;
        bsrc[j] = B + (size_t)brow[j] * IDIM + bblk[j] * 8;
    }

    v4f acc[4][4];
#pragma unroll
    for (int i = 0; i < 4; i++)
#pragma unroll
        for (int j = 0; j < 4; j++) acc[i][j] = (v4f)0.f;

    float4 br0[4], br1[4];
#pragma unroll
    for (int j = 0; j < 4; j++) {
        br0[j] = *(const float4*)(bsrc[j]);
        br1[j] = *(const float4*)(bsrc[j] + 4);
    }

    for (int ki = 0; ki < 8; ki++) {
        int kc = ki * 64;
        __syncthreads();
#pragma unroll
        for (int j = 0; j < 4; j++)
            GLL16(h + (size_t)(row0 + wave * 32 + j * 8 + rr) * IDIM + kc + cbl * 8,
                  As + wave * 2048 + j * 512);
#pragma unroll
        for (int j = 0; j < 4; j++) {
            uint4 p;
            p.x = (unsigned)f2bf(br0[j].x) | ((unsigned)f2bf(br0[j].y) << 16);
            p.y = (unsigned)f2bf(br0[j].z) | ((unsigned)f2bf(br0[j].w) << 16);
            p.z = (unsigned)f2bf(br1[j].x) | ((unsigned)f2bf(br1[j].y) << 16);
            p.w = (unsigned)f2bf(br1[j].z) | ((unsigned)f2bf(br1[j].w) << 16);
            *(uint4*)(Bs + brow[j] * 64 + ((bblk[j] ^ (brow[j] & 7)) * 8)) = p;
        }
        __syncthreads();
        if (ki < 7) {
#pragma unroll
            for (int j = 0; j < 4; j++) {
                br0[j] = *(const float4*)(bsrc[j] + kc + 64);
                br1[j] = *(const float4*)(bsrc[j] + kc + 68);
            }
        }
#pragma unroll
        for (int ks = 0; ks < 2; ks++) {
            int kb = ks * 4 + mq;
            v8s a[4], b[4];
#pragma unroll
            for (int mi = 0; mi < 4; mi++) {
                int R = wm * 64 + mi * 16 + nl;
                a[mi] = *(const v8s*)(As + R * 64 + ((kb ^ (nl & 7)) * 8));
            }
#pragma unroll
            for (int ni = 0; ni < 4; ni++) {
                int S = wn * 64 + ni * 16 + nl;
                b[ni] = *(const v8s*)(Bs + S * 64 + ((kb ^ (nl & 7)) * 8));
            }
#pragma unroll
            for (int mi = 0; mi < 4; mi++)
#pragma unroll
                for (int ni = 0; ni < 4; ni++)
                    acc[mi][ni] = __builtin_amdgcn_mfma_f32_16x16x32_bf16(a[mi], b[ni], acc[mi][ni], 0, 0, 0);
        }
    }
#pragma unroll
    for (int mi = 0; mi < 4; mi++) {
#pragma unroll
        for (int r = 0; r < 4; r++) {
            int srow = row0 + wm * 64 + mi * 16 + mq * 4 + r;
            if (srow < rend) {
                unsigned short* yrow = yp + ((size_t)srow << 10) + n0 + wn * 64 + nl;
#pragma unroll
                for (int ni = 0; ni < 4; ni++)
                    yrow[ni * 16] = f2bf(acc[mi][ni][r]);
            }
        }
    }
}

// ---------------- combine: out[t] = yp[shared_t] + sum of 4 routed yp rows ----------------
__global__ __launch_bounds__(256) void combine_kernel(
    const unsigned short* __restrict__ yp, const int* __restrict__ slotof,
    float* __restrict__ out)
{
    int t = blockIdx.x;
    int c = threadIdx.x * 4;
    int s0 = slotof[t * 4 + 0], s1 = slotof[t * 4 + 1];
    int s2 = slotof[t * 4 + 2], s3 = slotof[t * 4 + 3];
    ushort4 v  = *(const ushort4*)(yp + (((size_t)(S_ROUTED + t)) << 10) + c);
    ushort4 a0 = *(const ushort4*)(yp + (((size_t)s0) << 10) + c);
    ushort4 a1 = *(const ushort4*)(yp + (((size_t)s1) << 10) + c);
    ushort4 a2 = *(const ushort4*)(yp + (((size_t)s2) << 10) + c);
    ushort4 a3 = *(const ushort4*)(yp + (((size_t)s3) << 10) + c);
    float4 o;
    o.x = bf2f(v.x) + bf2f(a0.x) + bf2f(a1.x) + bf2f(a2.x) + bf2f(a3.x);
    o.y = bf2f(v.y) + bf2f(a0.y) + bf2f(a1.y) + bf2f(a2.y) + bf2f(a3.y);
    o.z = bf2f(v.z) + bf2f(a0.z) + bf2f(a1.z) + bf2f(a2.z) + bf2f(a3.z);
    o.w = bf2f(v.w) + bf2f(a0.w) + bf2f(a1.w) + bf2f(a2.w) + bf2f(a3.w);
    *(float4*)(out + (((size_t)t) << 10) + c) = o;
}

extern "C" void kernel_launch(void* const* d_in, const int* in_sizes, int n_in,
                              void* d_out, int out_size, void* d_ws, size_t ws_size,
                              hipStream_t stream) {
    const float* x    = (const float*)d_in[0];
    const float* gw   = (const float*)d_in[1];
    const float* w1   = (const float*)d_in[2];
    const float* w2   = (const float*)d_in[3];
    const float* w3   = (const float*)d_in[4];
    const float* wsh1 = (const float*)d_in[5];
    const float* wsh2 = (const float*)d_in[6];
    const float* wsh3 = (const float*)d_in[7];
    float* out = (float*)d_out;

    char* ws = (char*)d_ws;
    int*   topki  = (int*)(ws + OFF_TOPKI);
    float* topkw  = (float*)(ws + OFF_TOPKW);
    int*   part   = (int*)(ws + OFF_PART);
    int*   cbase  = (int*)(ws + OFF_CBASE);
    int*   segoff = (int*)(ws + OFF_SEGOFF);
    int*   ntp    = (int*)(ws + OFF_NTILES);
    int*   trow   = (int*)(ws + OFF_TROW);
    int*   tend   = (int*)(ws + OFF_TEND);
    int*   texp   = (int*)(ws + OFF_TEXP);
    float* slotwt = (float*)(ws + OFF_SLOTWT);
    int*   s2t    = (int*)(ws + OFF_S2T);
    int*   slotof = (int*)(ws + OFF_SLOTOF);
    unsigned short* xbf = (unsigned short*)(ws + OFF_XBF);
    unsigned short* h   = (unsigned short*)(ws + OFF_H);
    unsigned short* yp  = (unsigned short*)(ws + OFF_YP);

    gate_kernel<<<T_TOK, 256, 0, stream>>>(x, gw, topki, topkw, xbf);
    hist_kernel<<<32, 256, 0, stream>>>(topki, part);
    scan_kernel<<<1, 256, 0, stream>>>(part, cbase, segoff, trow, tend, texp, ntp);
    assign_kernel<<<32, 256, 0, stream>>>(topki, topkw, cbase, s2t, slotwt, slotof);
    gemm1_kernel<<<MAXTILE * 8, 256, 0, stream>>>(w1, w3, wsh1, wsh3, xbf, h, slotwt, s2t,
                                                  trow, tend, texp, ntp);
    gemm2_kernel<<<MAXTILE * 8, 256, 0, stream>>>(w2, wsh2, h, yp, trow, tend, texp, ntp);
    combine_kernel<<<T_TOK, 256, 0, stream>>>(yp, slotof, out);
}